// Round 27
// baseline (141.814 us; speedup 1.0000x reference)
//
#include <hip/hip_runtime.h>
#include <hip/hip_bf16.h>

// Problem constants (static per reference)
#define D 128
#define H 64
#define R 4
#define NT 64      // nodes per tile/block (4 waves x 16 rows)
#define LDC 132    // LDS stride (floats) for the per-wave strip
#define CAP 64     // per-node edge bucket capacity (deg ~ Poisson(16); P(>64) ~ 2e-18)
#define CCAP 4608  // coarse bin capacity (mean 4096 = 256 nodes * 16, +8 sigma)
#define EPB 2048   // edges per binA block

// MFMA fragment types
typedef __attribute__((ext_vector_type(8))) short bf16x8;
typedef __attribute__((ext_vector_type(4))) float f32x4;

// Weight-prep layout: per relation, 56 frags of 512 bf16 elems (64 lanes x 8):
//   W1 frags [0,16), W2 [16,24), W3 [24,40), Wu1_{r+1} [40,56)
// Updater block appended at UBASE: Wu1[0:128] [0,16), Wu2 [16,24), Wu3 [24,40)
// Frag f = ntile*KSTEPS + kstep; lane l covers col = ntile*16+(l&15),
// k = kstep*32 + (l>>4)*8 + i.  (Same phi used for A -> phi cancels.)
#define PREL 56
#define PFRAG 512
#define UBASE (R * PREL)     // 224
#define UPREL 40
#define NFRAG (UBASE + UPREL)

__device__ __forceinline__ float4 relu4(float4 v) {
    return make_float4(fmaxf(v.x, 0.f), fmaxf(v.y, 0.f), fmaxf(v.z, 0.f), fmaxf(v.w, 0.f));
}

// fp32 -> bf16 with round-to-nearest-even
__device__ __forceinline__ unsigned short f2bf_rne(float x) {
    unsigned u = __float_as_uint(x);
    return (unsigned short)((u + 0x7fffu + ((u >> 16) & 1u)) >> 16);
}

// split fp32 -> bf16 hi (RTZ) + bf16 lo (residual, RTZ)
__device__ __forceinline__ void split1(float x, short& hi, short& lo) {
    unsigned u = __float_as_uint(x);
    unsigned hb = u & 0xffff0000u;
    float res = x - __uint_as_float(hb);
    hi = (short)(u >> 16);
    lo = (short)(__float_as_uint(res) >> 16);
}

__device__ __forceinline__ void split8(const float* x8, bf16x8& hi, bf16x8& lo) {
#pragma unroll
    for (int i = 0; i < 8; ++i) {
        short h, l;
        split1(x8[i], h, l);
        hi[i] = h; lo[i] = l;
    }
}

__device__ __forceinline__ void load_split_A(const float* ap, bf16x8& ah, bf16x8& al) {
    float x8[8];
    *(float4*)&x8[0] = *(const float4*)ap;
    *(float4*)&x8[4] = *(const float4*)(ap + 4);
    split8(x8, ah, al);
}

// pre-split a strip's A-fragments for KSTEPS k-steps into registers
template<int KSTEPS>
__device__ __forceinline__ void split_strip_A(const float* Ws, int lane, bf16x8* ah, bf16x8* al) {
#pragma unroll
    for (int ks = 0; ks < KSTEPS; ++ks)
        load_split_A(Ws + (lane & 15) * LDC + ks * 32 + ((lane >> 4) << 3), ah[ks], al[ks]);
}

// async global->LDS, 16 B per lane (global src per-lane, LDS dst wave-uniform base)
__device__ __forceinline__ void gload_lds16(const void* g, void* l) {
    __builtin_amdgcn_global_load_lds(
        (const __attribute__((address_space(1))) void*)g,
        (__attribute__((address_space(3))) void*)l, 16, 0, 0);
}

// stage one 8-frag chunk (hi only) into an LDS buffer, cooperatively across 4 waves
__device__ __forceinline__ void stage_chunk(const short* __restrict__ srcH,
                                            short* BbH, int w, int lane) {
#pragma unroll
    for (int f = w; f < 8; f += 4)
        gload_lds16(srcH + ((size_t)f << 9) + (lane << 3), BbH + (f << 9));
}

// compute one 8-frag chunk: NCH = 8/KSTEPS n-tiles. A from registers,
// B-hi from LDS (staged), B-lo from global (batched, latency-tolerant).
template<int NCH, int KSTEPS>
__device__ __forceinline__ void compute_chunk(const bf16x8* ah, const bf16x8* al,
                                              const short* BbH,
                                              const short* __restrict__ BloG,
                                              int lane, f32x4* acc) {
#pragma unroll
    for (int ks = 0; ks < KSTEPS; ++ks) {
        bf16x8 bh[NCH], bl[NCH];
#pragma unroll
        for (int n = 0; n < NCH; ++n) {
            int f = n * KSTEPS + ks;
            bh[n] = *(const bf16x8*)(BbH + ((f * 64 + lane) << 3));
            bl[n] = *(const bf16x8*)(BloG + (((size_t)f * 64 + lane) << 3));
        }
#pragma unroll
        for (int n = 0; n < NCH; ++n) {
            acc[n] = __builtin_amdgcn_mfma_f32_16x16x32_bf16(ah[ks], bh[n], acc[n], 0, 0, 0);
            acc[n] = __builtin_amdgcn_mfma_f32_16x16x32_bf16(ah[ks], bl[n], acc[n], 0, 0, 0);
            acc[n] = __builtin_amdgcn_mfma_f32_16x16x32_bf16(al[ks], bh[n], acc[n], 0, 0, 0);
        }
    }
}

// bias + relu + store C strip to LDS fp32 (C/D layout: col=lane&15, row=(lane>>4)*4+reg)
template<int NT_TILES>
__device__ __forceinline__ void store_C_lds(const f32x4* acc, const float* __restrict__ bias,
                                            float* Ld, int ld, int lane) {
    int r0 = (lane >> 4) << 2;
#pragma unroll
    for (int n = 0; n < NT_TILES; ++n) {
        int col = n * 16 + (lane & 15);
        float bv = bias[col];
#pragma unroll
        for (int q = 0; q < 4; ++q)
            Ld[(r0 + q) * ld + col] = fmaxf(acc[n][q] + bv, 0.f);
    }
}

// ---------------- Merged prep: weight split/swizzle (blocks 0..18) + binA (rest) ----------------

__global__ __launch_bounds__(256) void k_prep(
    const float* __restrict__ W1, const float* __restrict__ W2,
    const float* __restrict__ W3, const float* __restrict__ Wu1,
    const float* __restrict__ Wu2, const float* __restrict__ Wu3,
    short* __restrict__ Phi, short* __restrict__ Plo,
    const int* __restrict__ esrc, const int* __restrict__ dst,
    const int* __restrict__ etype, int* __restrict__ gcnt,
    int2* __restrict__ coarse, int E, int NB)
{
    __shared__ int hist[256];
    __shared__ int base[256];
    const int t = threadIdx.x;

    if (blockIdx.x < 19) {
        // ---- weight prep ----
        int pair = blockIdx.x;
        const float* src; int KS, NTl, fragbase, ncol;
        if (pair < 16) {
            int r = pair >> 2, mat = pair & 3;
            if (mat == 0)      { src = W1  + (size_t)r * (D * H);       KS = 4; NTl = 4; fragbase = r * PREL + 0;  ncol = 64;  }
            else if (mat == 1) { src = W2  + (size_t)r * (H * H);       KS = 2; NTl = 4; fragbase = r * PREL + 16; ncol = 64;  }
            else if (mat == 2) { src = W3  + (size_t)r * (H * D);       KS = 2; NTl = 8; fragbase = r * PREL + 24; ncol = 128; }
            else               { src = Wu1 + (size_t)(r + 1) * D * H;   KS = 4; NTl = 4; fragbase = r * PREL + 40; ncol = 64;  }
        } else {
            int mat = pair - 16;
            if (mat == 0)      { src = Wu1; KS = 4; NTl = 4; fragbase = UBASE + 0;  ncol = 64;  }  // rows 0..127
            else if (mat == 1) { src = Wu2; KS = 2; NTl = 4; fragbase = UBASE + 16; ncol = 64;  }
            else               { src = Wu3; KS = 2; NTl = 8; fragbase = UBASE + 24; ncol = 128; }
        }
        int nf = NTl * KS;
        for (int u = t; u < nf * 64; u += 256) {
            int f = u >> 6, lane = u & 63;
            int n = f / KS, ks = f - n * KS;
            int col = n * 16 + (lane & 15);
            int k0 = ks * 32 + ((lane >> 4) << 3);
            size_t dstp = (((size_t)(fragbase + f)) * 64 + (size_t)lane) * 8;
#pragma unroll
            for (int i = 0; i < 8; ++i) {
                short h, l;
                split1(src[(size_t)(k0 + i) * ncol + col], h, l);
                Phi[dstp + i] = h;
                Plo[dstp + i] = l;
            }
        }
        return;
    }

    // ---- binA: LDS-binned coarse counting sort ----
    const int e0 = (blockIdx.x - 19) * EPB;
    hist[t] = 0;
    __syncthreads();
    int dsav[8], rsav[8];
#pragma unroll
    for (int j = 0; j < 8; ++j) {
        int e = e0 + j * 256 + t;
        int d = -1, rk = 0;
        if (e < E) {
            d = dst[e];
            rk = atomicAdd(&hist[d >> 8], 1);
        }
        dsav[j] = d; rsav[j] = rk;
    }
    __syncthreads();
    if (t < NB) base[t] = atomicAdd(&gcnt[t], hist[t]);
    __syncthreads();
#pragma unroll
    for (int j = 0; j < 8; ++j) {
        int e = e0 + j * 256 + t;
        int d = dsav[j];
        if (d >= 0) {
            int bin = d >> 8;
            int pos = base[bin] + rsav[j];
            if (pos < CCAP)
                coarse[(size_t)bin * CCAP + pos] = make_int2(d, esrc[e] * 4 + etype[e]);
        }
    }
}

// ---------------- Merged: binB (blocks 0..NB-1, retire fast) + message MLP (rest) ----------------
// MLP: hybrid B (hi double-buffered in LDS, lo from global), relation-major.
// LDS = 50176 B => 3 blocks/CU.

__global__ __launch_bounds__(256, 3) void k_mlp_bin(
    const float* __restrict__ X,
    const float* __restrict__ b1, const float* __restrict__ b2, const float* __restrict__ b3,
    const short* __restrict__ Phi, const short* __restrict__ Plo,
    unsigned short* __restrict__ U, int N, int tiles,
    const int2* __restrict__ coarse, const int* __restrict__ gcnt,
    int* __restrict__ cnt, int* __restrict__ eidx, int NB)
{
    __shared__ float Bsh[NT * LDC];        // per-wave 16-row strips (binB reuses as lcnt)
    __shared__ short BbH[2][8 * PFRAG];    // ping-pong B hi (8 KB each)

    const int tid = threadIdx.x;
    const int bid = blockIdx.x;

    if (bid < NB) {
        // ---- binB: scatter coarse bin -> per-node buckets ----
        int* lcnt = (int*)Bsh;
        lcnt[tid] = 0;
        __syncthreads();
        int m = gcnt[bid]; if (m > CCAP) m = CCAP;
        const int2* cp = coarse + (size_t)bid * CCAP;
        for (int i = tid; i < m; i += 256) {
            int2 pr = cp[i];
            int p = atomicAdd(&lcnt[pr.x & 255], 1);
            if (p < CAP) eidx[(size_t)pr.x * CAP + p] = pr.y;
        }
        __syncthreads();
        int node = (bid << 8) + tid;
        if (node < N) cnt[node] = lcnt[tid];
        return;
    }

    const int mi = bid - NB;
    const int lane = tid & 63;
    const int w = tid >> 6;
    const int m16 = w * 16;
    const int r = mi / tiles;                  // relation-major
    const int n0 = (mi - r * tiles) * NT;

    const short* PH = Phi + (size_t)(r * PREL) * PFRAG;
    const short* PL = Plo + (size_t)(r * PREL) * PFRAG;
    const float* b1r = b1 + r * H;
    const float* b2r = b2 + r * H;
    const float* b3r = b3 + r * D;

    float* Ws = &Bsh[m16 * LDC];   // this wave's strip

    // prologue: stage c0 (W1 frags 0:8) and c1 (W1 frags 8:16) hi-planes
    stage_chunk(PH,             BbH[0], w, lane);
    stage_chunk(PH + 8 * PFRAG, BbH[1], w, lane);

    // stage X A-fragments direct from global into registers, split once
    bf16x8 ahx[4], alx[4];
    {
        int row = n0 + m16 + (lane & 15);
        const float* xp = X + (size_t)row * D + ((lane >> 4) << 3);
        bool ok = (row < N);
#pragma unroll
        for (int ks = 0; ks < 4; ++ks) {
            float x8[8];
            if (ok) {
                *(float4*)&x8[0] = *(const float4*)(xp + ks * 32);
                *(float4*)&x8[4] = *(const float4*)(xp + ks * 32 + 4);
            } else {
#pragma unroll
                for (int i = 0; i < 8; ++i) x8[i] = 0.f;
            }
            split8(x8, ahx[ks], alx[ks]);
        }
    }
    __syncthreads();   // c0, c1 hi ready

    // ---- layer 1: X(16x128) @ W1(128x64), A from registers ----
    f32x4 acc[8];
#pragma unroll
    for (int n = 0; n < 4; ++n) acc[n] = (f32x4){0.f, 0.f, 0.f, 0.f};
    compute_chunk<2, 4>(ahx, alx, BbH[0], PL, lane, acc + 0);                 // n 0,1
    __syncthreads();                                                          // buf0 free
    stage_chunk(PH + 16 * PFRAG, BbH[0], w, lane);                            // c2 = W2
    compute_chunk<2, 4>(ahx, alx, BbH[1], PL + 8 * PFRAG, lane, acc + 2);     // n 2,3
    store_C_lds<4>(acc, b1r, Ws, LDC, lane);                                  // H1
    __syncthreads();                                                          // buf1 free; c2 ready
    stage_chunk(PH + 24 * PFRAG, BbH[1], w, lane);                            // c3 = W3[0:8]

    // ---- layer 2: H1(16x64) @ W2(64x64) ----
    bf16x8 a2h[2], a2l[2];
    split_strip_A<2>(Ws, lane, a2h, a2l);
#pragma unroll
    for (int n = 0; n < 4; ++n) acc[n] = (f32x4){0.f, 0.f, 0.f, 0.f};
    compute_chunk<4, 2>(a2h, a2l, BbH[0], PL + 16 * PFRAG, lane, acc);        // W2
    store_C_lds<4>(acc, b2r, Ws, LDC, lane);                                  // H2
    __syncthreads();                                                          // buf0 free; c3 ready
    stage_chunk(PH + 32 * PFRAG, BbH[0], w, lane);                            // c4 = W3[8:16]

    // ---- layer 3: H2(16x64) @ W3(64x128), relu -> T ----
    bf16x8 a3h[2], a3l[2];
    split_strip_A<2>(Ws, lane, a3h, a3l);
#pragma unroll
    for (int n = 0; n < 8; ++n) acc[n] = (f32x4){0.f, 0.f, 0.f, 0.f};
    compute_chunk<4, 2>(a3h, a3l, BbH[1], PL + 24 * PFRAG, lane, acc + 0);    // n 0..3
    __syncthreads();                                                          // buf1 free; c4 ready
    stage_chunk(PH + 40 * PFRAG, BbH[1], w, lane);                            // c5 = Wu[0:8]
    compute_chunk<4, 2>(a3h, a3l, BbH[0], PL + 32 * PFRAG, lane, acc + 4);    // n 4..7
    store_C_lds<8>(acc, b3r, Ws, LDC, lane);                                  // T
    __syncthreads();                                                          // buf0 free; c5 ready
    stage_chunk(PH + 48 * PFRAG, BbH[0], w, lane);                            // c6 = Wu[8:16]

    // ---- U projection: T(16x128) @ Wu1_{r+1}(128x64), store bf16 (RNE) ----
    bf16x8 auh[4], aul[4];
    split_strip_A<4>(Ws, lane, auh, aul);
    f32x4 accu[4];
#pragma unroll
    for (int n = 0; n < 4; ++n) accu[n] = (f32x4){0.f, 0.f, 0.f, 0.f};
    compute_chunk<2, 4>(auh, aul, BbH[1], PL + 40 * PFRAG, lane, accu + 0);   // n 0,1
    __syncthreads();                                                          // c6 ready
    compute_chunk<2, 4>(auh, aul, BbH[0], PL + 48 * PFRAG, lane, accu + 2);   // n 2,3
    {
        int r0 = (lane >> 4) << 2;
#pragma unroll
        for (int n = 0; n < 4; ++n) {
            int col = n * 16 + (lane & 15);
#pragma unroll
            for (int q = 0; q < 4; ++q) {
                int node = n0 + m16 + r0 + q;
                if (node < N)
                    U[((size_t)node * R + r) * H + col] = f2bf_rne(accu[n][q]);
            }
        }
    }
}

// ---------------- Stage B: gather S[n] = sum over in-edges of U[src*4+rel] ----------------
// U rows are 64 bf16 = 128 B; 32 lanes x uint (2 bf16). 16 edges in flight/wave.

__global__ __launch_bounds__(256) void k_gather(
    const unsigned int* __restrict__ U32,   // U viewed as uint pairs
    const int* __restrict__ cnt, const int* __restrict__ eidx,
    float* __restrict__ S, int N)
{
    const int wid = threadIdx.x >> 6, lane = threadIdx.x & 63;
    const int n = blockIdx.x * 4 + wid;
    if (n >= N) return;
    int g = cnt[n]; if (g > CAP) g = CAP;
    const int* ep = eidx + (size_t)n * CAP;
    const int half = lane >> 5;      // which edge of each pair
    const int c2 = lane & 31;        // uint column (2 bf16)
    float ax = 0.f, ay = 0.f;
    {
        int m = g;
        int v = 0;
        if (lane < m) v = ep[lane];
        for (int j0 = 0; j0 < m; j0 += 16) {
            int lim = m - j0; if (lim > 16) lim = 16;
            unsigned t[8];
#pragma unroll
            for (int p = 0; p < 8; ++p) {
                int vi = __shfl(v, j0 + 2 * p + half);
                bool ok = (2 * p + half) < lim;
                t[p] = ok ? U32[(size_t)vi * 32 + c2] : 0u;   // 16 edges in flight
            }
#pragma unroll
            for (int p = 0; p < 8; ++p) {
                ax += __uint_as_float(t[p] << 16);            // low bf16
                ay += __uint_as_float(t[p] & 0xffff0000u);    // high bf16
            }
        }
    }
    ax += __shfl_xor(ax, 32);
    ay += __shfl_xor(ay, 32);
    if (half == 0)
        *(float2*)&S[(size_t)n * H + (c2 << 1)] = make_float2(ax, ay);
}

// ---------------- Stage C: updater MLP + select (hybrid staged B, mirroring mlp) ----------------
// Hi-planes of Wu1/Wu2/Wu3 ping-pong staged in LDS (5 chunks), lo from global.
// LDS = 33792 + 16384 = 50176 B => 3 blocks/CU.

__global__ __launch_bounds__(256, 3) void k_upd(
    const float* __restrict__ X, const float* __restrict__ S,
    const int* __restrict__ cnt, const int* __restrict__ node_type,
    const short* __restrict__ Phi, const short* __restrict__ Plo,
    const float* __restrict__ bu1, const float* __restrict__ bu2, const float* __restrict__ bu3,
    float* __restrict__ out, int N)
{
    __shared__ float Hsh[NT * LDC];        // per-wave strips (H1/H2)
    __shared__ short UbH[2][8 * PFRAG];    // ping-pong B hi (8 KB each)

    const int tid = threadIdx.x;
    const int lane = tid & 63;
    const int w = tid >> 6;
    const int m16 = w * 16;
    const int n0 = blockIdx.x * NT;

    const short* PH = Phi + (size_t)UBASE * PFRAG;
    const short* PL = Plo + (size_t)UBASE * PFRAG;

    float* Ws = &Hsh[m16 * LDC];

    // prologue: stage c0 (Wu1 frags 0:8) and c1 (Wu1 frags 8:16) hi-planes
    stage_chunk(PH,             UbH[0], w, lane);
    stage_chunk(PH + 8 * PFRAG, UbH[1], w, lane);

    // stage chunk0 = relu(x) * (indeg > 0) direct into register A-fragments
    bf16x8 ahx[4], alx[4];
    {
        int row = n0 + m16 + (lane & 15);
        bool ok = (row < N) && (cnt[row] > 0);
        const float* xp = X + (size_t)row * D + ((lane >> 4) << 3);
#pragma unroll
        for (int ks = 0; ks < 4; ++ks) {
            float x8[8];
            if (ok) {
                float4 a = *(const float4*)(xp + ks * 32);
                float4 b = *(const float4*)(xp + ks * 32 + 4);
                a = relu4(a); b = relu4(b);
                *(float4*)&x8[0] = a;
                *(float4*)&x8[4] = b;
            } else {
#pragma unroll
                for (int i = 0; i < 8; ++i) x8[i] = 0.f;
            }
            split8(x8, ahx[ks], alx[ks]);
        }
    }
    __syncthreads();   // c0, c1 hi ready

    // ---- layer 1: chunk0 @ Wu1[0:128] + S + bu1, relu -> H1 ----
    f32x4 acc[8];
#pragma unroll
    for (int n = 0; n < 4; ++n) acc[n] = (f32x4){0.f, 0.f, 0.f, 0.f};
    compute_chunk<2, 4>(ahx, alx, UbH[0], PL, lane, acc + 0);                 // n 0,1
    __syncthreads();                                                          // buf0 free
    stage_chunk(PH + 16 * PFRAG, UbH[0], w, lane);                            // c2 = Wu2
    compute_chunk<2, 4>(ahx, alx, UbH[1], PL + 8 * PFRAG, lane, acc + 2);     // n 2,3
    {
        int r0 = (lane >> 4) << 2;
#pragma unroll
        for (int n = 0; n < 4; ++n) {
            int col = n * 16 + (lane & 15);
            float bv = bu1[col];
#pragma unroll
            for (int q = 0; q < 4; ++q) {
                int node = n0 + m16 + r0 + q;
                float sv = (node < N) ? S[(size_t)node * H + col] : 0.f;
                Ws[(r0 + q) * LDC + col] = fmaxf(acc[n][q] + bv + sv, 0.f);
            }
        }
    }
    __syncthreads();                                                          // buf1 free; c2 ready
    stage_chunk(PH + 24 * PFRAG, UbH[1], w, lane);                            // c3 = Wu3[0:8]

    // ---- layer 2: H1 @ Wu2, relu -> H2 (in place) ----
    bf16x8 a2h[2], a2l[2];
    split_strip_A<2>(Ws, lane, a2h, a2l);
#pragma unroll
    for (int n = 0; n < 4; ++n) acc[n] = (f32x4){0.f, 0.f, 0.f, 0.f};
    compute_chunk<4, 2>(a2h, a2l, UbH[0], PL + 16 * PFRAG, lane, acc);        // Wu2
    store_C_lds<4>(acc, bu2, Ws, LDC, lane);                                  // H2
    __syncthreads();                                                          // buf0 free; c3 ready
    stage_chunk(PH + 32 * PFRAG, UbH[0], w, lane);                            // c4 = Wu3[8:16]

    // ---- layer 3: H2 @ Wu3 (linear) + select by node_type ----
    bf16x8 a3h[2], a3l[2];
    split_strip_A<2>(Ws, lane, a3h, a3l);
#pragma unroll
    for (int n = 0; n < 8; ++n) acc[n] = (f32x4){0.f, 0.f, 0.f, 0.f};
    compute_chunk<4, 2>(a3h, a3l, UbH[1], PL + 24 * PFRAG, lane, acc + 0);    // n 0..3
    __syncthreads();                                                          // c4 ready
    compute_chunk<4, 2>(a3h, a3l, UbH[0], PL + 32 * PFRAG, lane, acc + 4);    // n 4..7
    {
        int r0 = (lane >> 4) << 2;
#pragma unroll
        for (int q = 0; q < 4; ++q) {
            int node = n0 + m16 + r0 + q;
            if (node >= N) continue;
            int t = node_type[node];
#pragma unroll
            for (int n = 0; n < 8; ++n) {
                int col = n * 16 + (lane & 15);
                float o = (t <= 1) ? (acc[n][q] + bu3[col])
                                   : X[(size_t)node * D + col];
                out[(size_t)node * D + col] = o;
            }
        }
    }
}

extern "C" void kernel_launch(void* const* d_in, const int* in_sizes, int n_in,
                              void* d_out, int out_size, void* d_ws, size_t ws_size,
                              hipStream_t stream) {
    const float* X     = (const float*)d_in[0];
    const int*   src   = (const int*)d_in[1];
    const int*   dst   = (const int*)d_in[2];
    const int*   etype = (const int*)d_in[3];
    const int*   ntype = (const int*)d_in[4];
    const float* W1    = (const float*)d_in[5];
    const float* b1    = (const float*)d_in[6];
    const float* W2    = (const float*)d_in[7];
    const float* b2    = (const float*)d_in[8];
    const float* W3    = (const float*)d_in[9];
    const float* b3    = (const float*)d_in[10];
    const float* Wu1   = (const float*)d_in[11];
    const float* bu1   = (const float*)d_in[12];
    const float* Wu2   = (const float*)d_in[13];
    const float* bu2   = (const float*)d_in[14];
    const float* Wu3   = (const float*)d_in[15];
    const float* bu3   = (const float*)d_in[16];
    float* out = (float*)d_out;

    const int N = in_sizes[4];
    const int E = in_sizes[1];
    const int NB = (N + 255) >> 8;     // coarse bins (196 for N=50000)

    // workspace layout
    unsigned short* U = (unsigned short*)d_ws;        // N*R*H bf16 (25.6 MB)
    float* S    = (float*)(U + (size_t)N * R * H);    // N*H floats (12.8 MB)
    int* cnt    = (int*)(S + (size_t)N * H);          // N (written fully by binB)
    int* gcnt   = cnt + N;                            // NB (zeroed by memset)
    int* eidx   = gcnt + 256;                         // N*CAP ints (12.8 MB)
    int2* coarse = (int2*)(eidx + (size_t)N * CAP);   // NB*CCAP int2 (7.2 MB)
    short* Phi  = (short*)(coarse + (size_t)NB * CCAP);
    short* Plo  = Phi + (size_t)NFRAG * PFRAG;

    hipMemsetAsync(gcnt, 0, 256 * sizeof(int), stream);

    int binAB = (E + EPB - 1) / EPB;
    k_prep<<<19 + binAB, 256, 0, stream>>>(W1, W2, W3, Wu1, Wu2, Wu3, Phi, Plo,
                                           src, dst, etype, gcnt, coarse, E, NB);

    int tiles = (N + NT - 1) / NT;
    k_mlp_bin<<<NB + tiles * R, 256, 0, stream>>>(X, b1, b2, b3, Phi, Plo, U, N, tiles,
                                                  coarse, gcnt, cnt, eidx, NB);
    k_gather<<<(N + 3) / 4, 256, 0, stream>>>((const unsigned int*)U, cnt, eidx, S, N);
    k_upd<<<tiles, 256, 0, stream>>>(X, S, cnt, ntype, Phi, Plo, bu1, bu2, bu3, out, N);
}

// Round 28
// 132.292 us; speedup vs baseline: 1.0720x; 1.0720x over previous
//
#include <hip/hip_runtime.h>
#include <hip/hip_bf16.h>

// Problem constants (static per reference)
#define D 128
#define H 64
#define R 4
#define NT 64      // nodes per tile/block (4 waves x 16 rows)
#define LDC 132    // LDS stride (floats) for the per-wave strip
#define CAP 64     // per-node edge bucket capacity (deg ~ Poisson(16); P(>64) ~ 2e-18)
#define CCAP 4608  // coarse bin capacity (mean 4096 = 256 nodes * 16, +8 sigma)
#define EPB 2048   // edges per binA block

// MFMA fragment types
typedef __attribute__((ext_vector_type(8))) short bf16x8;
typedef __attribute__((ext_vector_type(4))) float f32x4;

// Weight-prep layout: per relation, 56 frags of 512 bf16 elems (64 lanes x 8):
//   W1 frags [0,16), W2 [16,24), W3 [24,40), Wu1_{r+1} [40,56)
// Updater block appended at UBASE: Wu1[0:128] [0,16), Wu2 [16,24), Wu3 [24,40)
// Frag f = ntile*KSTEPS + kstep; lane l covers col = ntile*16+(l&15),
// k = kstep*32 + (l>>4)*8 + i.  (Same phi used for A -> phi cancels.)
#define PREL 56
#define PFRAG 512
#define UBASE (R * PREL)     // 224
#define UPREL 40
#define NFRAG (UBASE + UPREL)

__device__ __forceinline__ float4 relu4(float4 v) {
    return make_float4(fmaxf(v.x, 0.f), fmaxf(v.y, 0.f), fmaxf(v.z, 0.f), fmaxf(v.w, 0.f));
}

// fp32 -> bf16 with round-to-nearest-even
__device__ __forceinline__ unsigned short f2bf_rne(float x) {
    unsigned u = __float_as_uint(x);
    return (unsigned short)((u + 0x7fffu + ((u >> 16) & 1u)) >> 16);
}

// split fp32 -> bf16 hi (RTZ) + bf16 lo (residual, RTZ)
__device__ __forceinline__ void split1(float x, short& hi, short& lo) {
    unsigned u = __float_as_uint(x);
    unsigned hb = u & 0xffff0000u;
    float res = x - __uint_as_float(hb);
    hi = (short)(u >> 16);
    lo = (short)(__float_as_uint(res) >> 16);
}

__device__ __forceinline__ void split8(const float* x8, bf16x8& hi, bf16x8& lo) {
#pragma unroll
    for (int i = 0; i < 8; ++i) {
        short h, l;
        split1(x8[i], h, l);
        hi[i] = h; lo[i] = l;
    }
}

__device__ __forceinline__ void load_split_A(const float* ap, bf16x8& ah, bf16x8& al) {
    float x8[8];
    *(float4*)&x8[0] = *(const float4*)ap;
    *(float4*)&x8[4] = *(const float4*)(ap + 4);
    split8(x8, ah, al);
}

// pre-split a strip's A-fragments for KSTEPS k-steps into registers
template<int KSTEPS>
__device__ __forceinline__ void split_strip_A(const float* Ws, int lane, bf16x8* ah, bf16x8* al) {
#pragma unroll
    for (int ks = 0; ks < KSTEPS; ++ks)
        load_split_A(Ws + (lane & 15) * LDC + ks * 32 + ((lane >> 4) << 3), ah[ks], al[ks]);
}

// async global->LDS, 16 B per lane (global src per-lane, LDS dst wave-uniform base)
__device__ __forceinline__ void gload_lds16(const void* g, void* l) {
    __builtin_amdgcn_global_load_lds(
        (const __attribute__((address_space(1))) void*)g,
        (__attribute__((address_space(3))) void*)l, 16, 0, 0);
}

// stage one 8-frag chunk (hi only) into an LDS buffer, cooperatively across 4 waves
__device__ __forceinline__ void stage_chunk(const short* __restrict__ srcH,
                                            short* BbH, int w, int lane) {
#pragma unroll
    for (int f = w; f < 8; f += 4)
        gload_lds16(srcH + ((size_t)f << 9) + (lane << 3), BbH + (f << 9));
}

// compute one 8-frag chunk: NCH = 8/KSTEPS n-tiles. A from registers,
// B-hi from LDS (staged), B-lo from global (batched, latency-tolerant).
template<int NCH, int KSTEPS>
__device__ __forceinline__ void compute_chunk(const bf16x8* ah, const bf16x8* al,
                                              const short* BbH,
                                              const short* __restrict__ BloG,
                                              int lane, f32x4* acc) {
#pragma unroll
    for (int ks = 0; ks < KSTEPS; ++ks) {
        bf16x8 bh[NCH], bl[NCH];
#pragma unroll
        for (int n = 0; n < NCH; ++n) {
            int f = n * KSTEPS + ks;
            bh[n] = *(const bf16x8*)(BbH + ((f * 64 + lane) << 3));
            bl[n] = *(const bf16x8*)(BloG + (((size_t)f * 64 + lane) << 3));
        }
#pragma unroll
        for (int n = 0; n < NCH; ++n) {
            acc[n] = __builtin_amdgcn_mfma_f32_16x16x32_bf16(ah[ks], bh[n], acc[n], 0, 0, 0);
            acc[n] = __builtin_amdgcn_mfma_f32_16x16x32_bf16(ah[ks], bl[n], acc[n], 0, 0, 0);
            acc[n] = __builtin_amdgcn_mfma_f32_16x16x32_bf16(al[ks], bh[n], acc[n], 0, 0, 0);
        }
    }
}

// A from LDS fp32 strip (split on the fly), B from global (k_upd path)
template<int NT_TILES, int KSTEPS>
__device__ __forceinline__ void mfma_layer(const float* Als, int ld,
                                           const short* __restrict__ Bhi,
                                           const short* __restrict__ Blo,
                                           int lane, f32x4* acc) {
#pragma unroll
    for (int ks = 0; ks < KSTEPS; ++ks) {
        bf16x8 ah, al;
        load_split_A(Als + (lane & 15) * ld + ks * 32 + ((lane >> 4) << 3), ah, al);
        bf16x8 bh[NT_TILES], bl[NT_TILES];
#pragma unroll
        for (int n = 0; n < NT_TILES; ++n) {
            int f = n * KSTEPS + ks;
            bh[n] = *(const bf16x8*)(Bhi + (((size_t)f * 64 + lane) << 3));
            bl[n] = *(const bf16x8*)(Blo + (((size_t)f * 64 + lane) << 3));
        }
#pragma unroll
        for (int n = 0; n < NT_TILES; ++n) {
            acc[n] = __builtin_amdgcn_mfma_f32_16x16x32_bf16(ah, bh[n], acc[n], 0, 0, 0);
            acc[n] = __builtin_amdgcn_mfma_f32_16x16x32_bf16(ah, bl[n], acc[n], 0, 0, 0);
            acc[n] = __builtin_amdgcn_mfma_f32_16x16x32_bf16(al, bh[n], acc[n], 0, 0, 0);
        }
    }
}

template<int NT_TILES, int KSTEPS>
__device__ __forceinline__ void mfma_layer_regA(const bf16x8* ah, const bf16x8* al,
                                                const short* __restrict__ Bhi,
                                                const short* __restrict__ Blo,
                                                int lane, f32x4* acc) {
#pragma unroll
    for (int ks = 0; ks < KSTEPS; ++ks) {
        bf16x8 bh[NT_TILES], bl[NT_TILES];
#pragma unroll
        for (int n = 0; n < NT_TILES; ++n) {
            int f = n * KSTEPS + ks;
            bh[n] = *(const bf16x8*)(Bhi + (((size_t)f * 64 + lane) << 3));
            bl[n] = *(const bf16x8*)(Blo + (((size_t)f * 64 + lane) << 3));
        }
#pragma unroll
        for (int n = 0; n < NT_TILES; ++n) {
            acc[n] = __builtin_amdgcn_mfma_f32_16x16x32_bf16(ah[ks], bh[n], acc[n], 0, 0, 0);
            acc[n] = __builtin_amdgcn_mfma_f32_16x16x32_bf16(ah[ks], bl[n], acc[n], 0, 0, 0);
            acc[n] = __builtin_amdgcn_mfma_f32_16x16x32_bf16(al[ks], bh[n], acc[n], 0, 0, 0);
        }
    }
}

// bias + relu + store C strip to LDS fp32 (C/D layout: col=lane&15, row=(lane>>4)*4+reg)
template<int NT_TILES>
__device__ __forceinline__ void store_C_lds(const f32x4* acc, const float* __restrict__ bias,
                                            float* Ld, int ld, int lane) {
    int r0 = (lane >> 4) << 2;
#pragma unroll
    for (int n = 0; n < NT_TILES; ++n) {
        int col = n * 16 + (lane & 15);
        float bv = bias[col];
#pragma unroll
        for (int q = 0; q < 4; ++q)
            Ld[(r0 + q) * ld + col] = fmaxf(acc[n][q] + bv, 0.f);
    }
}

// ---------------- Merged prep: weight split/swizzle (blocks 0..18) + binA (rest) ----------------

__global__ __launch_bounds__(256) void k_prep(
    const float* __restrict__ W1, const float* __restrict__ W2,
    const float* __restrict__ W3, const float* __restrict__ Wu1,
    const float* __restrict__ Wu2, const float* __restrict__ Wu3,
    short* __restrict__ Phi, short* __restrict__ Plo,
    const int* __restrict__ esrc, const int* __restrict__ dst,
    const int* __restrict__ etype, int* __restrict__ gcnt,
    int2* __restrict__ coarse, int E, int NB)
{
    __shared__ int hist[256];
    __shared__ int base[256];
    const int t = threadIdx.x;

    if (blockIdx.x < 19) {
        // ---- weight prep ----
        int pair = blockIdx.x;
        const float* src; int KS, NTl, fragbase, ncol;
        if (pair < 16) {
            int r = pair >> 2, mat = pair & 3;
            if (mat == 0)      { src = W1  + (size_t)r * (D * H);       KS = 4; NTl = 4; fragbase = r * PREL + 0;  ncol = 64;  }
            else if (mat == 1) { src = W2  + (size_t)r * (H * H);       KS = 2; NTl = 4; fragbase = r * PREL + 16; ncol = 64;  }
            else if (mat == 2) { src = W3  + (size_t)r * (H * D);       KS = 2; NTl = 8; fragbase = r * PREL + 24; ncol = 128; }
            else               { src = Wu1 + (size_t)(r + 1) * D * H;   KS = 4; NTl = 4; fragbase = r * PREL + 40; ncol = 64;  }
        } else {
            int mat = pair - 16;
            if (mat == 0)      { src = Wu1; KS = 4; NTl = 4; fragbase = UBASE + 0;  ncol = 64;  }  // rows 0..127
            else if (mat == 1) { src = Wu2; KS = 2; NTl = 4; fragbase = UBASE + 16; ncol = 64;  }
            else               { src = Wu3; KS = 2; NTl = 8; fragbase = UBASE + 24; ncol = 128; }
        }
        int nf = NTl * KS;
        for (int u = t; u < nf * 64; u += 256) {
            int f = u >> 6, lane = u & 63;
            int n = f / KS, ks = f - n * KS;
            int col = n * 16 + (lane & 15);
            int k0 = ks * 32 + ((lane >> 4) << 3);
            size_t dstp = (((size_t)(fragbase + f)) * 64 + (size_t)lane) * 8;
#pragma unroll
            for (int i = 0; i < 8; ++i) {
                short h, l;
                split1(src[(size_t)(k0 + i) * ncol + col], h, l);
                Phi[dstp + i] = h;
                Plo[dstp + i] = l;
            }
        }
        return;
    }

    // ---- binA: LDS-binned coarse counting sort ----
    const int e0 = (blockIdx.x - 19) * EPB;
    hist[t] = 0;
    __syncthreads();
    int dsav[8], rsav[8];
#pragma unroll
    for (int j = 0; j < 8; ++j) {
        int e = e0 + j * 256 + t;
        int d = -1, rk = 0;
        if (e < E) {
            d = dst[e];
            rk = atomicAdd(&hist[d >> 8], 1);
        }
        dsav[j] = d; rsav[j] = rk;
    }
    __syncthreads();
    if (t < NB) base[t] = atomicAdd(&gcnt[t], hist[t]);
    __syncthreads();
#pragma unroll
    for (int j = 0; j < 8; ++j) {
        int e = e0 + j * 256 + t;
        int d = dsav[j];
        if (d >= 0) {
            int bin = d >> 8;
            int pos = base[bin] + rsav[j];
            if (pos < CCAP)
                coarse[(size_t)bin * CCAP + pos] = make_int2(d, esrc[e] * 4 + etype[e]);
        }
    }
}

// ---------------- Merged: binB (blocks 0..NB-1, retire fast) + message MLP (rest) ----------------
// MLP: hybrid B (hi double-buffered in LDS, lo from global), relation-major.
// LDS = 50176 B => 3 blocks/CU.

__global__ __launch_bounds__(256, 3) void k_mlp_bin(
    const float* __restrict__ X,
    const float* __restrict__ b1, const float* __restrict__ b2, const float* __restrict__ b3,
    const short* __restrict__ Phi, const short* __restrict__ Plo,
    unsigned short* __restrict__ U, int N, int tiles,
    const int2* __restrict__ coarse, const int* __restrict__ gcnt,
    int* __restrict__ cnt, int* __restrict__ eidx, int NB)
{
    __shared__ float Bsh[NT * LDC];        // per-wave 16-row strips (binB reuses as lcnt)
    __shared__ short BbH[2][8 * PFRAG];    // ping-pong B hi (8 KB each)

    const int tid = threadIdx.x;
    const int bid = blockIdx.x;

    if (bid < NB) {
        // ---- binB: scatter coarse bin -> per-node buckets ----
        int* lcnt = (int*)Bsh;
        lcnt[tid] = 0;
        __syncthreads();
        int m = gcnt[bid]; if (m > CCAP) m = CCAP;
        const int2* cp = coarse + (size_t)bid * CCAP;
        for (int i = tid; i < m; i += 256) {
            int2 pr = cp[i];
            int p = atomicAdd(&lcnt[pr.x & 255], 1);
            if (p < CAP) eidx[(size_t)pr.x * CAP + p] = pr.y;
        }
        __syncthreads();
        int node = (bid << 8) + tid;
        if (node < N) cnt[node] = lcnt[tid];
        return;
    }

    const int mi = bid - NB;
    const int lane = tid & 63;
    const int w = tid >> 6;
    const int m16 = w * 16;
    const int r = mi / tiles;                  // relation-major
    const int n0 = (mi - r * tiles) * NT;

    const short* PH = Phi + (size_t)(r * PREL) * PFRAG;
    const short* PL = Plo + (size_t)(r * PREL) * PFRAG;
    const float* b1r = b1 + r * H;
    const float* b2r = b2 + r * H;
    const float* b3r = b3 + r * D;

    float* Ws = &Bsh[m16 * LDC];   // this wave's strip

    // prologue: stage c0 (W1 frags 0:8) and c1 (W1 frags 8:16) hi-planes
    stage_chunk(PH,             BbH[0], w, lane);
    stage_chunk(PH + 8 * PFRAG, BbH[1], w, lane);

    // stage X A-fragments direct from global into registers, split once
    bf16x8 ahx[4], alx[4];
    {
        int row = n0 + m16 + (lane & 15);
        const float* xp = X + (size_t)row * D + ((lane >> 4) << 3);
        bool ok = (row < N);
#pragma unroll
        for (int ks = 0; ks < 4; ++ks) {
            float x8[8];
            if (ok) {
                *(float4*)&x8[0] = *(const float4*)(xp + ks * 32);
                *(float4*)&x8[4] = *(const float4*)(xp + ks * 32 + 4);
            } else {
#pragma unroll
                for (int i = 0; i < 8; ++i) x8[i] = 0.f;
            }
            split8(x8, ahx[ks], alx[ks]);
        }
    }
    __syncthreads();   // c0, c1 hi ready

    // ---- layer 1: X(16x128) @ W1(128x64), A from registers ----
    f32x4 acc[8];
#pragma unroll
    for (int n = 0; n < 4; ++n) acc[n] = (f32x4){0.f, 0.f, 0.f, 0.f};
    compute_chunk<2, 4>(ahx, alx, BbH[0], PL, lane, acc + 0);                 // n 0,1
    __syncthreads();                                                          // buf0 free
    stage_chunk(PH + 16 * PFRAG, BbH[0], w, lane);                            // c2 = W2
    compute_chunk<2, 4>(ahx, alx, BbH[1], PL + 8 * PFRAG, lane, acc + 2);     // n 2,3
    store_C_lds<4>(acc, b1r, Ws, LDC, lane);                                  // H1
    __syncthreads();                                                          // buf1 free; c2 ready
    stage_chunk(PH + 24 * PFRAG, BbH[1], w, lane);                            // c3 = W3[0:8]

    // ---- layer 2: H1(16x64) @ W2(64x64) ----
    bf16x8 a2h[2], a2l[2];
    split_strip_A<2>(Ws, lane, a2h, a2l);
#pragma unroll
    for (int n = 0; n < 4; ++n) acc[n] = (f32x4){0.f, 0.f, 0.f, 0.f};
    compute_chunk<4, 2>(a2h, a2l, BbH[0], PL + 16 * PFRAG, lane, acc);        // W2
    store_C_lds<4>(acc, b2r, Ws, LDC, lane);                                  // H2
    __syncthreads();                                                          // buf0 free; c3 ready
    stage_chunk(PH + 32 * PFRAG, BbH[0], w, lane);                            // c4 = W3[8:16]

    // ---- layer 3: H2(16x64) @ W3(64x128), relu -> T ----
    bf16x8 a3h[2], a3l[2];
    split_strip_A<2>(Ws, lane, a3h, a3l);
#pragma unroll
    for (int n = 0; n < 8; ++n) acc[n] = (f32x4){0.f, 0.f, 0.f, 0.f};
    compute_chunk<4, 2>(a3h, a3l, BbH[1], PL + 24 * PFRAG, lane, acc + 0);    // n 0..3
    __syncthreads();                                                          // buf1 free; c4 ready
    stage_chunk(PH + 40 * PFRAG, BbH[1], w, lane);                            // c5 = Wu[0:8]
    compute_chunk<4, 2>(a3h, a3l, BbH[0], PL + 32 * PFRAG, lane, acc + 4);    // n 4..7
    store_C_lds<8>(acc, b3r, Ws, LDC, lane);                                  // T
    __syncthreads();                                                          // buf0 free; c5 ready
    stage_chunk(PH + 48 * PFRAG, BbH[0], w, lane);                            // c6 = Wu[8:16]

    // ---- U projection: T(16x128) @ Wu1_{r+1}(128x64), store bf16 (RNE) ----
    bf16x8 auh[4], aul[4];
    split_strip_A<4>(Ws, lane, auh, aul);
    f32x4 accu[4];
#pragma unroll
    for (int n = 0; n < 4; ++n) accu[n] = (f32x4){0.f, 0.f, 0.f, 0.f};
    compute_chunk<2, 4>(auh, aul, BbH[1], PL + 40 * PFRAG, lane, accu + 0);   // n 0,1
    __syncthreads();                                                          // c6 ready
    compute_chunk<2, 4>(auh, aul, BbH[0], PL + 48 * PFRAG, lane, accu + 2);   // n 2,3
    {
        int r0 = (lane >> 4) << 2;
#pragma unroll
        for (int n = 0; n < 4; ++n) {
            int col = n * 16 + (lane & 15);
#pragma unroll
            for (int q = 0; q < 4; ++q) {
                int node = n0 + m16 + r0 + q;
                if (node < N)
                    U[((size_t)node * R + r) * H + col] = f2bf_rne(accu[n][q]);
            }
        }
    }
}

// ---------------- Stage B: gather S[n] = sum over in-edges of U[src*4+rel] ----------------
// U rows are 64 bf16 = 128 B; 32 lanes x uint (2 bf16). 16 edges in flight/wave.

__global__ __launch_bounds__(256) void k_gather(
    const unsigned int* __restrict__ U32,   // U viewed as uint pairs
    const int* __restrict__ cnt, const int* __restrict__ eidx,
    float* __restrict__ S, int N)
{
    const int wid = threadIdx.x >> 6, lane = threadIdx.x & 63;
    const int n = blockIdx.x * 4 + wid;
    if (n >= N) return;
    int g = cnt[n]; if (g > CAP) g = CAP;
    const int* ep = eidx + (size_t)n * CAP;
    const int half = lane >> 5;      // which edge of each pair
    const int c2 = lane & 31;        // uint column (2 bf16)
    float ax = 0.f, ay = 0.f;
    {
        int m = g;
        int v = 0;
        if (lane < m) v = ep[lane];
        for (int j0 = 0; j0 < m; j0 += 16) {
            int lim = m - j0; if (lim > 16) lim = 16;
            unsigned t[8];
#pragma unroll
            for (int p = 0; p < 8; ++p) {
                int vi = __shfl(v, j0 + 2 * p + half);
                bool ok = (2 * p + half) < lim;
                t[p] = ok ? U32[(size_t)vi * 32 + c2] : 0u;   // 16 edges in flight
            }
#pragma unroll
            for (int p = 0; p < 8; ++p) {
                ax += __uint_as_float(t[p] << 16);            // low bf16
                ay += __uint_as_float(t[p] & 0xffff0000u);    // high bf16
            }
        }
    }
    ax += __shfl_xor(ax, 32);
    ay += __shfl_xor(ay, 32);
    if (half == 0)
        *(float2*)&S[(size_t)n * H + (c2 << 1)] = make_float2(ax, ay);
}

// ---------------- Stage C: updater MLP + select (split-bf16 MFMA, barrier-free) ----------------

__global__ __launch_bounds__(256, 4) void k_upd(
    const float* __restrict__ X, const float* __restrict__ S,
    const int* __restrict__ cnt, const int* __restrict__ node_type,
    const short* __restrict__ Phi, const short* __restrict__ Plo,
    const float* __restrict__ bu1, const float* __restrict__ bu2, const float* __restrict__ bu3,
    float* __restrict__ out, int N)
{
    __shared__ float Hsh[NT * LDC];   // per-wave strips (H1/H2)

    const int tid = threadIdx.x;
    const int lane = tid & 63;
    const int w = tid >> 6;
    const int m16 = w * 16;
    const int n0 = blockIdx.x * NT;

    const short* PH = Phi + (size_t)UBASE * PFRAG;
    const short* PL = Plo + (size_t)UBASE * PFRAG;

    float* Ws = &Hsh[m16 * LDC];

    // stage chunk0 = relu(x) * (indeg > 0) direct into register A-fragments
    bf16x8 ahx[4], alx[4];
    {
        int row = n0 + m16 + (lane & 15);
        bool ok = (row < N) && (cnt[row] > 0);
        const float* xp = X + (size_t)row * D + ((lane >> 4) << 3);
#pragma unroll
        for (int ks = 0; ks < 4; ++ks) {
            float x8[8];
            if (ok) {
                float4 a = *(const float4*)(xp + ks * 32);
                float4 b = *(const float4*)(xp + ks * 32 + 4);
                a = relu4(a); b = relu4(b);
                *(float4*)&x8[0] = a;
                *(float4*)&x8[4] = b;
            } else {
#pragma unroll
                for (int i = 0; i < 8; ++i) x8[i] = 0.f;
            }
            split8(x8, ahx[ks], alx[ks]);
        }
    }

    // layer 1: chunk0 @ Wu1[0:128] + S + bu1, relu -> H1
    f32x4 acc[8];
#pragma unroll
    for (int n = 0; n < 4; ++n) acc[n] = (f32x4){0.f, 0.f, 0.f, 0.f};
    mfma_layer_regA<4, 4>(ahx, alx, PH, PL, lane, acc);
    {
        int r0 = (lane >> 4) << 2;
#pragma unroll
        for (int n = 0; n < 4; ++n) {
            int col = n * 16 + (lane & 15);
            float bv = bu1[col];
#pragma unroll
            for (int q = 0; q < 4; ++q) {
                int node = n0 + m16 + r0 + q;
                float sv = (node < N) ? S[(size_t)node * H + col] : 0.f;
                Ws[(r0 + q) * LDC + col] = fmaxf(acc[n][q] + bv + sv, 0.f);
            }
        }
    }

    // layer 2: H1 @ Wu2, relu -> H2 (in place)
#pragma unroll
    for (int n = 0; n < 4; ++n) acc[n] = (f32x4){0.f, 0.f, 0.f, 0.f};
    mfma_layer<4, 2>(Ws, LDC, PH + (size_t)16 * PFRAG, PL + (size_t)16 * PFRAG, lane, acc);
    store_C_lds<4>(acc, bu2, Ws, LDC, lane);

    // layer 3: H2 @ Wu3 (linear) + select by node_type
#pragma unroll
    for (int n = 0; n < 8; ++n) acc[n] = (f32x4){0.f, 0.f, 0.f, 0.f};
    mfma_layer<8, 2>(Ws, LDC, PH + (size_t)24 * PFRAG, PL + (size_t)24 * PFRAG, lane, acc);
    {
        int r0 = (lane >> 4) << 2;
#pragma unroll
        for (int q = 0; q < 4; ++q) {
            int node = n0 + m16 + r0 + q;
            if (node >= N) continue;
            int t = node_type[node];
#pragma unroll
            for (int n = 0; n < 8; ++n) {
                int col = n * 16 + (lane & 15);
                float o = (t <= 1) ? (acc[n][q] + bu3[col])
                                   : X[(size_t)node * D + col];
                out[(size_t)node * D + col] = o;
            }
        }
    }
}

extern "C" void kernel_launch(void* const* d_in, const int* in_sizes, int n_in,
                              void* d_out, int out_size, void* d_ws, size_t ws_size,
                              hipStream_t stream) {
    const float* X     = (const float*)d_in[0];
    const int*   src   = (const int*)d_in[1];
    const int*   dst   = (const int*)d_in[2];
    const int*   etype = (const int*)d_in[3];
    const int*   ntype = (const int*)d_in[4];
    const float* W1    = (const float*)d_in[5];
    const float* b1    = (const float*)d_in[6];
    const float* W2    = (const float*)d_in[7];
    const float* b2    = (const float*)d_in[8];
    const float* W3    = (const float*)d_in[9];
    const float* b3    = (const float*)d_in[10];
    const float* Wu1   = (const float*)d_in[11];
    const float* bu1   = (const float*)d_in[12];
    const float* Wu2   = (const float*)d_in[13];
    const float* bu2   = (const float*)d_in[14];
    const float* Wu3   = (const float*)d_in[15];
    const float* bu3   = (const float*)d_in[16];
    float* out = (float*)d_out;

    const int N = in_sizes[4];
    const int E = in_sizes[1];
    const int NB = (N + 255) >> 8;     // coarse bins (196 for N=50000)

    // workspace layout
    unsigned short* U = (unsigned short*)d_ws;        // N*R*H bf16 (25.6 MB)
    float* S    = (float*)(U + (size_t)N * R * H);    // N*H floats (12.8 MB)
    int* cnt    = (int*)(S + (size_t)N * H);          // N (written fully by binB)
    int* gcnt   = cnt + N;                            // NB (zeroed by memset)
    int* eidx   = gcnt + 256;                         // N*CAP ints (12.8 MB)
    int2* coarse = (int2*)(eidx + (size_t)N * CAP);   // NB*CCAP int2 (7.2 MB)
    short* Phi  = (short*)(coarse + (size_t)NB * CCAP);
    short* Plo  = Phi + (size_t)NFRAG * PFRAG;

    hipMemsetAsync(gcnt, 0, 256 * sizeof(int), stream);

    int binAB = (E + EPB - 1) / EPB;
    k_prep<<<19 + binAB, 256, 0, stream>>>(W1, W2, W3, Wu1, Wu2, Wu3, Phi, Plo,
                                           src, dst, etype, gcnt, coarse, E, NB);

    int tiles = (N + NT - 1) / NT;
    k_mlp_bin<<<NB + tiles * R, 256, 0, stream>>>(X, b1, b2, b3, Phi, Plo, U, N, tiles,
                                                  coarse, gcnt, cnt, eidx, NB);
    k_gather<<<(N + 3) / 4, 256, 0, stream>>>((const unsigned int*)U, cnt, eidx, S, N);
    k_upd<<<tiles, 256, 0, stream>>>(X, S, cnt, ntype, Phi, Plo, bu1, bu2, bu3, out, N);
}